// Round 2
// baseline (1734.963 us; speedup 1.0000x reference)
//
#include <hip/hip_runtime.h>

#define NN 16384
#define DL 64
#define HD 128
#define BM 256          // rows per WG (4 waves x 64)
#define BN 64           // j per iteration
#define JS 8            // j splits -> grid 64 x 8 = 512 WGs
#define JCH (NN / JS)

typedef _Float16 v8h __attribute__((ext_vector_type(8)));
typedef float v16f __attribute__((ext_vector_type(16)));
typedef unsigned short ushort_t;
typedef unsigned int uint32;

__device__ __forceinline__ float bf2f(ushort_t v) {
  return __uint_as_float(((uint32)v) << 16);
}
__device__ __forceinline__ ushort_t f2bf(float f) {
  uint32 u = __float_as_uint(f);
  return (ushort_t)((u + 0x7FFFu + ((u >> 16) & 1u)) >> 16);
}
__device__ __forceinline__ uint32 pack2h(float a, float b) {
  union { _Float16 h; ushort_t s; } ua, ub;
  ua.h = (_Float16)a; ub.h = (_Float16)b;
  return (uint32)ua.s | ((uint32)ub.s << 16);
}
__device__ __forceinline__ void gld16(void* lds, const void* gp) {
  __builtin_amdgcn_global_load_lds(
      (const __attribute__((address_space(1))) uint32*)gp,
      (__attribute__((address_space(3))) uint32*)lds, 16, 0, 0);
}

// ---------------------------------------------------------------------------
// detect input dtype (bf16 vs fp32) from feat bit patterns; stash scalars.
// consts: [0]=isbf, [1]=t=1+temp, [2]=th=5+theta, [3]=s2=2*t*log2e
// ---------------------------------------------------------------------------
__global__ void detect_k(const void* __restrict__ feat,
                         const void* __restrict__ temp,
                         const void* __restrict__ theta,
                         float* __restrict__ consts) {
  if (threadIdx.x == 0) {
    const ushort_t* u = (const ushort_t*)feat;
    int sane = 0;
    for (int i = 0; i < 128; ++i) {
      float v = fabsf(bf2f(u[i]));
      if (v > 1e-4f && v < 16.0f) sane++;
    }
    int isbf = (sane >= 100) ? 1 : 0;
    float tv, th;
    if (isbf) {
      tv = bf2f(((const ushort_t*)temp)[0]);
      th = bf2f(((const ushort_t*)theta)[0]);
    } else {
      tv = ((const float*)temp)[0];
      th = ((const float*)theta)[0];
    }
    consts[0] = (float)isbf;
    consts[1] = 1.0f + tv;
    consts[2] = 5.0f + th;
    consts[3] = 2.0f * (1.0f + tv) * 1.44269504088896341f;
  }
}

// ---------------------------------------------------------------------------
// prep: g = relu(x@glw+glb) (fp16), hT = (x@gnw+gnb)^T (fp16 [128][N]),
//       crow = (0.5*th - t*sq)*log2e.  One wave per row.
// ---------------------------------------------------------------------------
template <int L0>
__global__ __launch_bounds__(256) void prep_k(
    const void* __restrict__ xb, const float* __restrict__ pmsg,
    const float* __restrict__ pden, const void* __restrict__ glw,
    const void* __restrict__ glb, const void* __restrict__ gnw,
    const void* __restrict__ gnb, const float* __restrict__ cst,
    _Float16* __restrict__ g, _Float16* __restrict__ hT,
    float* __restrict__ crow) {
  __shared__ float xr[4][128];
  const int w = threadIdx.x >> 6, l = threadIdx.x & 63;
  const int row = blockIdx.x * 4 + w;
  const int isbf = (cst[0] != 0.0f);
  float x0, x1;
  if (L0) {
    if (isbf) {
      const ushort_t* p = (const ushort_t*)xb;
      x0 = bf2f(p[row * 128 + 2 * l]);
      x1 = bf2f(p[row * 128 + 2 * l + 1]);
    } else {
      const float* p = (const float*)xb;
      x0 = p[row * 128 + 2 * l];
      x1 = p[row * 128 + 2 * l + 1];
    }
  } else {
    float rd = __builtin_amdgcn_rcpf(fmaxf(pden[row], 1e-10f));
    float m0 = pmsg[(size_t)row * 128 + 2 * l];
    float m1 = pmsg[(size_t)row * 128 + 2 * l + 1];
    x0 = fmaxf(m0 * rd, 0.0f);   // fmax scrubs NaN -> 0
    x1 = fmaxf(m1 * rd, 0.0f);
  }
  xr[w][2 * l] = x0;
  xr[w][2 * l + 1] = x1;
  __syncthreads();
  float ag = 0.0f, a0 = 0.0f, a1 = 0.0f;
  float bg, b0, b1;
  if (isbf) {
    const ushort_t* Wg = (const ushort_t*)glw;
    const ushort_t* Wn = (const ushort_t*)gnw;
#pragma unroll 8
    for (int k = 0; k < 128; ++k) {
      float xk = xr[w][k];
      ag = fmaf(xk, bf2f(Wg[k * 64 + l]), ag);
      a0 = fmaf(xk, bf2f(Wn[k * 128 + l]), a0);
      a1 = fmaf(xk, bf2f(Wn[k * 128 + 64 + l]), a1);
    }
    bg = bf2f(((const ushort_t*)glb)[l]);
    b0 = bf2f(((const ushort_t*)gnb)[l]);
    b1 = bf2f(((const ushort_t*)gnb)[64 + l]);
  } else {
    const float* Wg = (const float*)glw;
    const float* Wn = (const float*)gnw;
#pragma unroll 8
    for (int k = 0; k < 128; ++k) {
      float xk = xr[w][k];
      ag = fmaf(xk, Wg[k * 64 + l], ag);
      a0 = fmaf(xk, Wn[k * 128 + l], a0);
      a1 = fmaf(xk, Wn[k * 128 + 64 + l], a1);
    }
    bg = ((const float*)glb)[l];
    b0 = ((const float*)gnb)[l];
    b1 = ((const float*)gnb)[64 + l];
  }
  const float t = cst[1];
  const float th = cst[2];
  float gv = fmaxf(ag + bg, 0.0f);
  _Float16 gq = (_Float16)gv;
  g[(size_t)row * DL + l] = gq;
  float gf = (float)gq;
  float sq = gf * gf;
#pragma unroll
  for (int off = 1; off < 64; off <<= 1) sq += __shfl_xor(sq, off, 64);
  if (l == 0) crow[row] = (0.5f * th - t * sq) * 1.44269504088896341f;
  hT[(size_t)l * NN + row] = (_Float16)(a0 + b0);
  hT[(size_t)(l + 64) * NN + row] = (_Float16)(a1 + b1);
}

// ---------------------------------------------------------------------------
// fused sigmoid-attention: msg += P*H, den += P*1 (atomics), P = 256*sigmoid.
// ---------------------------------------------------------------------------
__global__ __launch_bounds__(256, 2) void attn_main(
    const _Float16* __restrict__ g, const _Float16* __restrict__ hT,
    const float* __restrict__ crow, const float* __restrict__ cst,
    float* __restrict__ msg, float* __restrict__ den) {
  __shared__ __align__(16) short SM[4096 + 8192];  // Gs 8KB + Hs 16KB
  _Float16* Gs = (_Float16*)SM;
  _Float16* Hs = (_Float16*)(SM + 4096);

  const int tid = threadIdx.x;
  const int w = tid >> 6;
  const int l = tid & 63;
  const int ln = l & 31;
  const int hb = l >> 5;
  const int iw = blockIdx.x * BM + w * 64;
  const int jb = blockIdx.y * JCH;
  const float s2 = cst[3];

  // persistent B-operand frags of G_i: B[n=i=lane&31][k]
  v8h Bi[2][4];
#pragma unroll
  for (int it = 0; it < 2; ++it)
#pragma unroll
    for (int kf = 0; kf < 4; ++kf)
      Bi[it][kf] =
          *(const v8h*)(g + (size_t)(iw + it * 32 + ln) * DL + kf * 16 + hb * 8);

  const float ci0 = crow[iw + ln];
  const float ci1 = crow[iw + 32 + ln];

  v16f o[4][2];
#pragma unroll
  for (int mp = 0; mp < 4; ++mp)
#pragma unroll
    for (int it = 0; it < 2; ++it)
#pragma unroll
      for (int r = 0; r < 16; ++r) o[mp][it][r] = 0.0f;

  float dp0 = 0.0f, dp1 = 0.0f;

#pragma unroll 1
  for (int itr = 0; itr < JCH / BN; ++itr) {
    const int j0 = jb + itr * BN;
    __syncthreads();
#pragma unroll
    for (int oo = 0; oo < 2; ++oo) {
      int c = oo * 256 + tid;
      int jj = c >> 3, pc = c & 7;
      int kc = pc ^ (jj & 7);
      gld16((char*)Gs + (oo * 256 + w * 64) * 16,
            g + (size_t)(j0 + jj) * DL + kc * 8);
    }
#pragma unroll
    for (int oo = 0; oo < 4; ++oo) {
      int c = oo * 256 + tid;
      int hc = c >> 3, pc = c & 7;
      int jc = pc ^ (hc & 7);
      gld16((char*)Hs + (oo * 256 + w * 64) * 16,
            hT + (size_t)hc * NN + j0 + jc * 8);
    }
    __syncthreads();

#pragma unroll
    for (int jt = 0; jt < 2; ++jt) {
      float cj[16];
#pragma unroll
      for (int q2 = 0; q2 < 4; ++q2) {
        float4 f4 = *(const float4*)(crow + j0 + jt * 32 + q2 * 8 + 4 * hb);
        cj[q2 * 4 + 0] = f4.x;
        cj[q2 * 4 + 1] = f4.y;
        cj[q2 * 4 + 2] = f4.z;
        cj[q2 * 4 + 3] = f4.w;
      }
      v16f sv[2];
#pragma unroll
      for (int r = 0; r < 16; ++r) {
        sv[0][r] = 0.0f;
        sv[1][r] = 0.0f;
      }
#pragma unroll
      for (int kf = 0; kf < 4; ++kf) {
        int row = jt * 32 + ln;
        int kc = kf * 2 + hb;
        v8h a = *(const v8h*)(Gs + row * 64 + ((kc ^ (row & 7)) * 8));
        sv[0] = __builtin_amdgcn_mfma_f32_32x32x16_f16(a, Bi[0][kf], sv[0], 0, 0, 0);
        sv[1] = __builtin_amdgcn_mfma_f32_32x32x16_f16(a, Bi[1][kf], sv[1], 0, 0, 0);
      }
      uint32 Bf[2][2][4];
#pragma unroll
      for (int it = 0; it < 2; ++it) {
        float pv[16];
        float dps = 0.0f;
        float cib = it ? ci1 : ci0;
#pragma unroll
        for (int r = 0; r < 16; ++r) {
          float arg = fmaf(s2, sv[it][r], cib) + cj[r];
          arg = fminf(fmaxf(arg, -60.0f), 60.0f);  // scrubs NaN, keeps sigmoid
          float e = __builtin_amdgcn_exp2f(-arg);
          float adj = 256.0f * __builtin_amdgcn_rcpf(1.0f + e);
          dps += adj;
          pv[r] = adj;
        }
        if (it == 0) dp0 += dps; else dp1 += dps;
#pragma unroll
        for (int kq = 0; kq < 2; ++kq) {
          int q = kq * 8;
          uint32 lo0 = pack2h(pv[q + 0], pv[q + 1]);
          uint32 lo1 = pack2h(pv[q + 2], pv[q + 3]);
          uint32 hi0 = pack2h(pv[q + 4], pv[q + 5]);
          uint32 hi1 = pack2h(pv[q + 6], pv[q + 7]);
          uint32 sl0 = (uint32)__shfl_xor((int)lo0, 32, 64);
          uint32 sl1 = (uint32)__shfl_xor((int)lo1, 32, 64);
          uint32 sh0 = (uint32)__shfl_xor((int)hi0, 32, 64);
          uint32 sh1 = (uint32)__shfl_xor((int)hi1, 32, 64);
          Bf[it][kq][0] = hb ? sh0 : lo0;
          Bf[it][kq][1] = hb ? sh1 : lo1;
          Bf[it][kq][2] = hb ? hi0 : sl0;
          Bf[it][kq][3] = hb ? hi1 : sl1;
        }
      }
#pragma unroll
      for (int kq = 0; kq < 2; ++kq) {
        union { uint32 u[4]; v8h v; } b0, b1;
        b0.u[0] = Bf[0][kq][0]; b0.u[1] = Bf[0][kq][1];
        b0.u[2] = Bf[0][kq][2]; b0.u[3] = Bf[0][kq][3];
        b1.u[0] = Bf[1][kq][0]; b1.u[1] = Bf[1][kq][1];
        b1.u[2] = Bf[1][kq][2]; b1.u[3] = Bf[1][kq][3];
        int kc = (jt * 2 + kq) * 2 + hb;
#pragma unroll
        for (int mp = 0; mp < 4; ++mp) {
          int hc = mp * 32 + ln;
          v8h Ah = *(const v8h*)(Hs + hc * 64 + ((kc ^ (hc & 7)) * 8));
          o[mp][0] = __builtin_amdgcn_mfma_f32_32x32x16_f16(Ah, b0.v, o[mp][0], 0, 0, 0);
          o[mp][1] = __builtin_amdgcn_mfma_f32_32x32x16_f16(Ah, b1.v, o[mp][1], 0, 0, 0);
        }
      }
    }
  }

  dp0 += __shfl_xor(dp0, 32, 64);
  dp1 += __shfl_xor(dp1, 32, 64);
  if (hb == 0) {
    atomicAdd(&den[iw + ln], dp0);
    atomicAdd(&den[iw + 32 + ln], dp1);
  }
  __syncthreads();
  float* Tw = ((float*)SM) + w * (32 * 33);
#pragma unroll
  for (int mp = 0; mp < 4; ++mp)
#pragma unroll
    for (int it = 0; it < 2; ++it) {
#pragma unroll
      for (int r = 0; r < 16; ++r) {
        int hl = (r & 3) + 8 * (r >> 2) + 4 * hb;
        Tw[ln * 33 + hl] = o[mp][it][r];
      }
#pragma unroll
      for (int rr = 0; rr < 16; ++rr) {
        int il = rr * 2 + hb;
        float v = Tw[il * 33 + ln];
        atomicAdd(&msg[(size_t)(iw + it * 32 + il) * HD + mp * 32 + ln], v);
      }
    }
}

// ---------------------------------------------------------------------------
// final: out = softmax((msg/den) @ out_w + out_b). 16 lanes per row.
// ---------------------------------------------------------------------------
__global__ __launch_bounds__(256) void final_k(
    const float* __restrict__ pmsg, const float* __restrict__ pden,
    const void* __restrict__ ow, const void* __restrict__ ob,
    const float* __restrict__ cst, void* __restrict__ out) {
  __shared__ float Ws[1280];
  const int isbf = (cst[0] != 0.0f);
  if (isbf) {
    for (int i = threadIdx.x; i < 1280; i += 256) Ws[i] = bf2f(((const ushort_t*)ow)[i]);
  } else {
    for (int i = threadIdx.x; i < 1280; i += 256) Ws[i] = ((const float*)ow)[i];
  }
  __syncthreads();
  const int l16 = threadIdx.x & 15, grp = threadIdx.x >> 4;
  const int row = blockIdx.x * 16 + grp;
  const float rd = __builtin_amdgcn_rcpf(fmaxf(pden[row], 1e-10f));
  float acc[10];
#pragma unroll
  for (int c = 0; c < 10; ++c) acc[c] = 0.0f;
#pragma unroll
  for (int kk = 0; kk < 8; ++kk) {
    int k = kk * 16 + l16;
    float xv = pmsg[(size_t)row * 128 + k] * rd;
    xv = fminf(fmaxf(xv, -1e6f), 1e6f);  // scrubs NaN
#pragma unroll
    for (int c = 0; c < 10; ++c) acc[c] = fmaf(xv, Ws[k * 10 + c], acc[c]);
  }
  float bias[10];
  if (isbf) {
#pragma unroll
    for (int c = 0; c < 10; ++c) bias[c] = bf2f(((const ushort_t*)ob)[c]);
  } else {
#pragma unroll
    for (int c = 0; c < 10; ++c) bias[c] = ((const float*)ob)[c];
  }
#pragma unroll
  for (int c = 0; c < 10; ++c) {
#pragma unroll
    for (int off = 1; off < 16; off <<= 1) acc[c] += __shfl_xor(acc[c], off, 64);
    acc[c] += bias[c];
  }
  float m = acc[0];
#pragma unroll
  for (int c = 1; c < 10; ++c) m = fmaxf(m, acc[c]);
  float s = 0.0f, e[10];
#pragma unroll
  for (int c = 0; c < 10; ++c) {
    e[c] = __builtin_amdgcn_exp2f((acc[c] - m) * 1.44269504088896341f);
    s += e[c];
  }
  float rs = __builtin_amdgcn_rcpf(s);
  float mine = e[0];
#pragma unroll
  for (int c = 1; c < 10; ++c) mine = (l16 == c) ? e[c] : mine;
  if (l16 < 10) {
    float v = mine * rs;
    if (isbf) ((ushort_t*)out)[(size_t)row * 10 + l16] = f2bf(v);
    else ((float*)out)[(size_t)row * 10 + l16] = v;
  }
}

// ---------------------------------------------------------------------------
extern "C" void kernel_launch(void* const* d_in, const int* in_sizes, int n_in,
                              void* d_out, int out_size, void* d_ws,
                              size_t ws_size, hipStream_t stream) {
  const void* feat = d_in[0];
  const void* glw0 = d_in[1];
  const void* glb0 = d_in[2];
  const void* glw1 = d_in[3];
  const void* glb1 = d_in[4];
  const void* gnw0 = d_in[5];
  const void* gnb0 = d_in[6];
  const void* gnw1 = d_in[7];
  const void* gnb1 = d_in[8];
  const void* ow = d_in[9];
  const void* obv = d_in[10];
  const void* temp = d_in[11];
  const void* thet = d_in[12];

  char* ws = (char*)d_ws;
  _Float16* g = (_Float16*)ws;                          // 2 MB
  _Float16* hT = (_Float16*)(ws + (size_t)(2u << 20));  // 4 MB
  float* crow = (float*)(ws + (size_t)(6u << 20));      // 64 KB
  float* msg = (float*)(ws + (size_t)(6u << 20) + (1u << 16));   // 8 MB
  float* den = (float*)(ws + (size_t)(14u << 20) + (1u << 16));  // 64 KB
  float* cst = (float*)(ws + (size_t)(15u << 20));      // 16 B

  dim3 b256(256);
  detect_k<<<dim3(1), dim3(64), 0, stream>>>(feat, temp, thet, cst);
  // layer 0
  prep_k<1><<<dim3(NN / 4), b256, 0, stream>>>(feat, nullptr, nullptr, glw0,
                                               glb0, gnw0, gnb0, cst, g, hT,
                                               crow);
  hipMemsetAsync(msg, 0, (size_t)NN * HD * 4, stream);
  hipMemsetAsync(den, 0, (size_t)NN * 4, stream);
  attn_main<<<dim3(NN / BM, JS), b256, 0, stream>>>(g, hT, crow, cst, msg, den);
  // layer 1
  prep_k<0><<<dim3(NN / 4), b256, 0, stream>>>(nullptr, msg, den, glw1, glb1,
                                               gnw1, gnb1, cst, g, hT, crow);
  hipMemsetAsync(msg, 0, (size_t)NN * HD * 4, stream);
  hipMemsetAsync(den, 0, (size_t)NN * 4, stream);
  attn_main<<<dim3(NN / BM, JS), b256, 0, stream>>>(g, hT, crow, cst, msg, den);
  // output layer + softmax
  final_k<<<dim3(NN / 16), b256, 0, stream>>>(msg, den, ow, obv, cst, d_out);
}

// Round 3
// 1674.970 us; speedup vs baseline: 1.0358x; 1.0358x over previous
//
#include <hip/hip_runtime.h>

#define NN 16384
#define DL 64
#define HD 128
#define BMW 32          // i-rows per wave
#define BM 128          // rows per WG (4 waves x 32)
#define BN 64           // j per iteration
#define JS 8            // j splits -> grid 128 x 8 = 1024 WGs
#define JCH (NN / JS)

typedef _Float16 v8h __attribute__((ext_vector_type(8)));
typedef float v16f __attribute__((ext_vector_type(16)));
typedef unsigned short ushort_t;
typedef unsigned int uint32;

__device__ __forceinline__ float bf2f(ushort_t v) {
  return __uint_as_float(((uint32)v) << 16);
}
__device__ __forceinline__ ushort_t f2bf(float f) {
  uint32 u = __float_as_uint(f);
  return (ushort_t)((u + 0x7FFFu + ((u >> 16) & 1u)) >> 16);
}
__device__ __forceinline__ uint32 pack2h(float a, float b) {
  union { _Float16 h; ushort_t s; } ua, ub;
  ua.h = (_Float16)a; ub.h = (_Float16)b;
  return (uint32)ua.s | ((uint32)ub.s << 16);
}
__device__ __forceinline__ void gld16(void* lds, const void* gp) {
  __builtin_amdgcn_global_load_lds(
      (const __attribute__((address_space(1))) uint32*)gp,
      (__attribute__((address_space(3))) uint32*)lds, 16, 0, 0);
}

// ---------------------------------------------------------------------------
// detect input dtype (bf16 vs fp32) from feat bit patterns; stash scalars.
// consts: [0]=isbf, [1]=t, [2]=th, [3]=s2
// ---------------------------------------------------------------------------
__global__ void detect_k(const void* __restrict__ feat,
                         const void* __restrict__ temp,
                         const void* __restrict__ theta,
                         float* __restrict__ consts) {
  const int l = threadIdx.x;  // 64 threads
  const ushort_t* u = (const ushort_t*)feat;
  float v0 = fabsf(bf2f(u[2 * l]));
  float v1 = fabsf(bf2f(u[2 * l + 1]));
  int ok = ((v0 > 1e-4f && v0 < 16.0f) ? 1 : 0) +
           ((v1 > 1e-4f && v1 < 16.0f) ? 1 : 0);
#pragma unroll
  for (int off = 1; off < 64; off <<= 1) ok += __shfl_xor(ok, off, 64);
  if (l == 0) {
    int isbf = (ok >= 100) ? 1 : 0;
    float tv, th;
    if (isbf) {
      tv = bf2f(((const ushort_t*)temp)[0]);
      th = bf2f(((const ushort_t*)theta)[0]);
    } else {
      tv = ((const float*)temp)[0];
      th = ((const float*)theta)[0];
    }
    consts[0] = (float)isbf;
    consts[1] = 1.0f + tv;
    consts[2] = 5.0f + th;
    consts[3] = 2.0f * (1.0f + tv) * 1.44269504088896341f;
  }
}

// ---------------------------------------------------------------------------
// prep: g = relu(x@glw+glb) (fp16), hT = (x@gnw+gnb)^T (fp16 [128][N]),
//       crow = (0.5*th - t*sq)*log2e.  One wave per row.
// L0=1: x from raw input. L0=0: x = relu(sum_js msgp / sum_js denp).
// ---------------------------------------------------------------------------
template <int L0>
__global__ __launch_bounds__(256) void prep_k(
    const void* __restrict__ xb, const float* __restrict__ msgp,
    const float* __restrict__ denp, const void* __restrict__ glw,
    const void* __restrict__ glb, const void* __restrict__ gnw,
    const void* __restrict__ gnb, const float* __restrict__ cst,
    _Float16* __restrict__ g, _Float16* __restrict__ hT,
    float* __restrict__ crow) {
  __shared__ float xr[4][128];
  const int w = threadIdx.x >> 6, l = threadIdx.x & 63;
  const int row = blockIdx.x * 4 + w;
  const int isbf = (cst[0] != 0.0f);
  float x0, x1;
  if (L0) {
    if (isbf) {
      const ushort_t* p = (const ushort_t*)xb;
      x0 = bf2f(p[row * 128 + 2 * l]);
      x1 = bf2f(p[row * 128 + 2 * l + 1]);
    } else {
      const float* p = (const float*)xb;
      x0 = p[row * 128 + 2 * l];
      x1 = p[row * 128 + 2 * l + 1];
    }
  } else {
    float m0 = 0.0f, m1 = 0.0f, d = 0.0f;
#pragma unroll
    for (int js = 0; js < JS; ++js) {
      const float* mp = msgp + (size_t)js * NN * HD + (size_t)row * HD;
      m0 += mp[2 * l];
      m1 += mp[2 * l + 1];
      d += denp[js * NN + row];
    }
    float rd = __builtin_amdgcn_rcpf(fmaxf(d, 1e-10f));
    x0 = fmaxf(m0 * rd, 0.0f);
    x1 = fmaxf(m1 * rd, 0.0f);
  }
  xr[w][2 * l] = x0;
  xr[w][2 * l + 1] = x1;
  __syncthreads();
  float ag = 0.0f, a0 = 0.0f, a1 = 0.0f;
  float bg, b0, b1;
  if (isbf) {
    const ushort_t* Wg = (const ushort_t*)glw;
    const ushort_t* Wn = (const ushort_t*)gnw;
#pragma unroll 8
    for (int k = 0; k < 128; ++k) {
      float xk = xr[w][k];
      ag = fmaf(xk, bf2f(Wg[k * 64 + l]), ag);
      a0 = fmaf(xk, bf2f(Wn[k * 128 + l]), a0);
      a1 = fmaf(xk, bf2f(Wn[k * 128 + 64 + l]), a1);
    }
    bg = bf2f(((const ushort_t*)glb)[l]);
    b0 = bf2f(((const ushort_t*)gnb)[l]);
    b1 = bf2f(((const ushort_t*)gnb)[64 + l]);
  } else {
    const float* Wg = (const float*)glw;
    const float* Wn = (const float*)gnw;
#pragma unroll 8
    for (int k = 0; k < 128; ++k) {
      float xk = xr[w][k];
      ag = fmaf(xk, Wg[k * 64 + l], ag);
      a0 = fmaf(xk, Wn[k * 128 + l], a0);
      a1 = fmaf(xk, Wn[k * 128 + 64 + l], a1);
    }
    bg = ((const float*)glb)[l];
    b0 = ((const float*)gnb)[l];
    b1 = ((const float*)gnb)[64 + l];
  }
  const float t = cst[1];
  const float th = cst[2];
  float gv = fmaxf(ag + bg, 0.0f);
  _Float16 gq = (_Float16)gv;
  g[(size_t)row * DL + l] = gq;
  float gf = (float)gq;
  float sq = gf * gf;
#pragma unroll
  for (int off = 1; off < 64; off <<= 1) sq += __shfl_xor(sq, off, 64);
  if (l == 0) crow[row] = (0.5f * th - t * sq) * 1.44269504088896341f;
  hT[(size_t)l * NN + row] = (_Float16)(a0 + b0);
  hT[(size_t)(l + 64) * NN + row] = (_Float16)(a1 + b1);
}

// ---------------------------------------------------------------------------
// fused sigmoid-attention: msgp[js] = P*H, denp[js] = P*1, P = 256*sigmoid.
// Wave owns 32 i-rows; plain coalesced stores to per-js partial buffers.
// ---------------------------------------------------------------------------
__global__ __launch_bounds__(256, 2) void attn_main(
    const _Float16* __restrict__ g, const _Float16* __restrict__ hT,
    const float* __restrict__ crow, const float* __restrict__ cst,
    float* __restrict__ msgp, float* __restrict__ denp) {
  __shared__ __align__(16) short SM[4096 + 8192];  // Gs 8KB + Hs 16KB
  _Float16* Gs = (_Float16*)SM;
  _Float16* Hs = (_Float16*)(SM + 4096);

  const int tid = threadIdx.x;
  const int w = tid >> 6;
  const int l = tid & 63;
  const int ln = l & 31;
  const int hb = l >> 5;
  const int iw = blockIdx.x * BM + w * BMW;
  const int jb = blockIdx.y * JCH;
  const float s2 = cst[3];

  // persistent B-operand frags of G_i: B[n=i=lane&31][k=kf*16+hb*8+e]
  v8h Bi[4];
#pragma unroll
  for (int kf = 0; kf < 4; ++kf)
    Bi[kf] = *(const v8h*)(g + (size_t)(iw + ln) * DL + kf * 16 + hb * 8);

  const float ci = crow[iw + ln];

  v16f o[4];  // O^T accum per h-block
#pragma unroll
  for (int mp = 0; mp < 4; ++mp)
#pragma unroll
    for (int r = 0; r < 16; ++r) o[mp][r] = 0.0f;

  float dp = 0.0f;

#pragma unroll 1
  for (int itr = 0; itr < JCH / BN; ++itr) {
    const int j0 = jb + itr * BN;
    __syncthreads();
#pragma unroll
    for (int oo = 0; oo < 2; ++oo) {
      int c = oo * 256 + tid;
      int jj = c >> 3, pc = c & 7;
      int kc = pc ^ (jj & 7);
      gld16((char*)Gs + (oo * 256 + w * 64) * 16,
            g + (size_t)(j0 + jj) * DL + kc * 8);
    }
#pragma unroll
    for (int oo = 0; oo < 4; ++oo) {
      int c = oo * 256 + tid;
      int hc = c >> 3, pc = c & 7;
      int jc = pc ^ (hc & 7);
      gld16((char*)Hs + (oo * 256 + w * 64) * 16,
            hT + (size_t)hc * NN + j0 + jc * 8);
    }
    __syncthreads();

#pragma unroll
    for (int jt = 0; jt < 2; ++jt) {
      float cj[16];
#pragma unroll
      for (int q2 = 0; q2 < 4; ++q2) {
        float4 f4 = *(const float4*)(crow + j0 + jt * 32 + q2 * 8 + 4 * hb);
        cj[q2 * 4 + 0] = f4.x;
        cj[q2 * 4 + 1] = f4.y;
        cj[q2 * 4 + 2] = f4.z;
        cj[q2 * 4 + 3] = f4.w;
      }
      // S^T = G_j * G_i^T
      v16f sv;
#pragma unroll
      for (int r = 0; r < 16; ++r) sv[r] = 0.0f;
#pragma unroll
      for (int kf = 0; kf < 4; ++kf) {
        int row = jt * 32 + ln;
        int kc = kf * 2 + hb;
        v8h a = *(const v8h*)(Gs + row * 64 + ((kc ^ (row & 7)) * 8));
        sv = __builtin_amdgcn_mfma_f32_32x32x16_f16(a, Bi[kf], sv, 0, 0, 0);
      }
      // sigmoid (x256)
      float pv[16];
      float dps = 0.0f;
#pragma unroll
      for (int r = 0; r < 16; ++r) {
        float arg = fmaf(s2, sv[r], ci) + cj[r];
        arg = fminf(fmaxf(arg, -60.0f), 60.0f);
        float e = __builtin_amdgcn_exp2f(-arg);
        float adj = 256.0f * __builtin_amdgcn_rcpf(1.0f + e);
        dps += adj;
        pv[r] = adj;
      }
      dp += dps;
      // P^T -> B-frags (pack + half-wave exchange), then O^T += H^T * P^T
#pragma unroll
      for (int kq = 0; kq < 2; ++kq) {
        int q = kq * 8;
        uint32 lo0 = pack2h(pv[q + 0], pv[q + 1]);
        uint32 lo1 = pack2h(pv[q + 2], pv[q + 3]);
        uint32 hi0 = pack2h(pv[q + 4], pv[q + 5]);
        uint32 hi1 = pack2h(pv[q + 6], pv[q + 7]);
        uint32 sl0 = (uint32)__shfl_xor((int)lo0, 32, 64);
        uint32 sl1 = (uint32)__shfl_xor((int)lo1, 32, 64);
        uint32 sh0 = (uint32)__shfl_xor((int)hi0, 32, 64);
        uint32 sh1 = (uint32)__shfl_xor((int)hi1, 32, 64);
        union { uint32 u[4]; v8h v; } b;
        b.u[0] = hb ? sh0 : lo0;
        b.u[1] = hb ? sh1 : lo1;
        b.u[2] = hb ? hi0 : sl0;
        b.u[3] = hb ? hi1 : sl1;
        int kc = (jt * 2 + kq) * 2 + hb;
#pragma unroll
        for (int mp = 0; mp < 4; ++mp) {
          int hc = mp * 32 + ln;
          v8h Ah = *(const v8h*)(Hs + hc * 64 + ((kc ^ (hc & 7)) * 8));
          o[mp] = __builtin_amdgcn_mfma_f32_32x32x16_f16(Ah, b.v, o[mp], 0, 0, 0);
        }
      }
    }
  }

  // epilogue: den partial (i on lanes)
  dp += __shfl_xor(dp, 32, 64);
  if (hb == 0) denp[blockIdx.y * NN + iw + ln] = dp;
  // msg partial: transpose 32x32 O^T tiles through LDS, coalesced stores
  __syncthreads();
  float* Tw = ((float*)SM) + w * (32 * 33);
  float* mout = msgp + (size_t)blockIdx.y * NN * HD;
#pragma unroll
  for (int mp = 0; mp < 4; ++mp) {
#pragma unroll
    for (int r = 0; r < 16; ++r) {
      int hl = (r & 3) + 8 * (r >> 2) + 4 * hb;
      Tw[ln * 33 + hl] = o[mp][r];
    }
#pragma unroll
    for (int rr = 0; rr < 16; ++rr) {
      int il = rr * 2 + hb;
      mout[(size_t)(iw + il) * HD + mp * 32 + ln] = Tw[il * 33 + ln];
    }
  }
}

// ---------------------------------------------------------------------------
// final: out = softmax((sum msgp / sum denp) @ out_w + out_b). 16 lanes/row.
// ---------------------------------------------------------------------------
__global__ __launch_bounds__(256) void final_k(
    const float* __restrict__ msgp, const float* __restrict__ denp,
    const void* __restrict__ ow, const void* __restrict__ ob,
    const float* __restrict__ cst, void* __restrict__ out) {
  __shared__ float Ws[1280];
  const int isbf = (cst[0] != 0.0f);
  if (isbf) {
    for (int i = threadIdx.x; i < 1280; i += 256) Ws[i] = bf2f(((const ushort_t*)ow)[i]);
  } else {
    for (int i = threadIdx.x; i < 1280; i += 256) Ws[i] = ((const float*)ow)[i];
  }
  __syncthreads();
  const int l16 = threadIdx.x & 15, grp = threadIdx.x >> 4;
  const int row = blockIdx.x * 16 + grp;
  float d = 0.0f;
#pragma unroll
  for (int js = 0; js < JS; ++js) d += denp[js * NN + row];
  const float rd = __builtin_amdgcn_rcpf(fmaxf(d, 1e-10f));
  float acc[10];
#pragma unroll
  for (int c = 0; c < 10; ++c) acc[c] = 0.0f;
#pragma unroll
  for (int kk = 0; kk < 8; ++kk) {
    int k = kk * 16 + l16;
    float m = 0.0f;
#pragma unroll
    for (int js = 0; js < JS; ++js)
      m += msgp[(size_t)js * NN * HD + (size_t)row * HD + k];
    float xv = m * rd;
    xv = fminf(fmaxf(xv, -1e6f), 1e6f);
#pragma unroll
    for (int c = 0; c < 10; ++c) acc[c] = fmaf(xv, Ws[k * 10 + c], acc[c]);
  }
  float bias[10];
  if (isbf) {
#pragma unroll
    for (int c = 0; c < 10; ++c) bias[c] = bf2f(((const ushort_t*)ob)[c]);
  } else {
#pragma unroll
    for (int c = 0; c < 10; ++c) bias[c] = ((const float*)ob)[c];
  }
#pragma unroll
  for (int c = 0; c < 10; ++c) {
#pragma unroll
    for (int off = 1; off < 16; off <<= 1) acc[c] += __shfl_xor(acc[c], off, 64);
    acc[c] += bias[c];
  }
  float m = acc[0];
#pragma unroll
  for (int c = 1; c < 10; ++c) m = fmaxf(m, acc[c]);
  float s = 0.0f, e[10];
#pragma unroll
  for (int c = 0; c < 10; ++c) {
    e[c] = __builtin_amdgcn_exp2f((acc[c] - m) * 1.44269504088896341f);
    s += e[c];
  }
  float rs = __builtin_amdgcn_rcpf(s);
  float mine = e[0];
#pragma unroll
  for (int c = 1; c < 10; ++c) mine = (l16 == c) ? e[c] : mine;
  if (l16 < 10) {
    float v = mine * rs;
    if (isbf) ((ushort_t*)out)[(size_t)row * 10 + l16] = f2bf(v);
    else ((float*)out)[(size_t)row * 10 + l16] = v;
  }
}

// ---------------------------------------------------------------------------
extern "C" void kernel_launch(void* const* d_in, const int* in_sizes, int n_in,
                              void* d_out, int out_size, void* d_ws,
                              size_t ws_size, hipStream_t stream) {
  const void* feat = d_in[0];
  const void* glw0 = d_in[1];
  const void* glb0 = d_in[2];
  const void* glw1 = d_in[3];
  const void* glb1 = d_in[4];
  const void* gnw0 = d_in[5];
  const void* gnb0 = d_in[6];
  const void* gnw1 = d_in[7];
  const void* gnb1 = d_in[8];
  const void* ow = d_in[9];
  const void* obv = d_in[10];
  const void* temp = d_in[11];
  const void* thet = d_in[12];

  char* ws = (char*)d_ws;
  _Float16* g = (_Float16*)ws;                          // 2 MB
  _Float16* hT = (_Float16*)(ws + (size_t)(2u << 20));  // 4 MB
  float* crow = (float*)(ws + (size_t)(6u << 20));      // 64 KB
  float* cst = (float*)(ws + (size_t)(6u << 20) + (1u << 16));  // 256 B
  float* msgp = (float*)(ws + (size_t)(7u << 20));      // 8 x 8 MB = 64 MB
  float* denp = (float*)(ws + (size_t)(71u << 20));     // 8 x 64 KB

  dim3 b256(256);
  detect_k<<<dim3(1), dim3(64), 0, stream>>>(feat, temp, thet, cst);
  // layer 0
  prep_k<1><<<dim3(NN / 4), b256, 0, stream>>>(feat, nullptr, nullptr, glw0,
                                               glb0, gnw0, gnb0, cst, g, hT,
                                               crow);
  attn_main<<<dim3(NN / BM, JS), b256, 0, stream>>>(g, hT, crow, cst, msgp,
                                                    denp);
  // layer 1
  prep_k<0><<<dim3(NN / 4), b256, 0, stream>>>(nullptr, msgp, denp, glw1, glb1,
                                               gnw1, gnb1, cst, g, hT, crow);
  attn_main<<<dim3(NN / BM, JS), b256, 0, stream>>>(g, hT, crow, cst, msgp,
                                                    denp);
  // output layer + softmax
  final_k<<<dim3(NN / 16), b256, 0, stream>>>(msgp, denp, ow, obv, cst, d_out);
}

// Round 5
// 1581.887 us; speedup vs baseline: 1.0968x; 1.0588x over previous
//
#include <hip/hip_runtime.h>

#define NN 16384
#define DL 64
#define HD 128
#define BMW 32          // i-rows per wave
#define BM 128          // rows per WG (4 waves x 32)
#define BN 64           // j per iteration
#define JS 8            // j splits -> grid 128 x 8 = 1024 WGs
#define JCH (NN / JS)
#define NITER (JCH / BN)

typedef _Float16 v8h __attribute__((ext_vector_type(8)));
typedef __fp16 v2fp16 __attribute__((ext_vector_type(2)));
typedef float v16f __attribute__((ext_vector_type(16)));
typedef unsigned short ushort_t;
typedef unsigned int uint32;

__device__ __forceinline__ float bf2f(ushort_t v) {
  return __uint_as_float(((uint32)v) << 16);
}
__device__ __forceinline__ ushort_t f2bf(float f) {
  uint32 u = __float_as_uint(f);
  return (ushort_t)((u + 0x7FFFu + ((u >> 16) & 1u)) >> 16);
}
__device__ __forceinline__ uint32 pack2h(float a, float b) {
  union { v2fp16 h; uint32 u; } p;
  p.h = __builtin_amdgcn_cvt_pkrtz(a, b);
  return p.u;
}
__device__ __forceinline__ void gld16(void* lds, const void* gp) {
  __builtin_amdgcn_global_load_lds(
      (const __attribute__((address_space(1))) uint32*)gp,
      (__attribute__((address_space(3))) uint32*)lds, 16, 0, 0);
}

// ---------------------------------------------------------------------------
// detect input dtype (bf16 vs fp32) from feat bit patterns; stash scalars.
// consts: [0]=isbf, [1]=t, [2]=th, [3]=s2
// ---------------------------------------------------------------------------
__global__ void detect_k(const void* __restrict__ feat,
                         const void* __restrict__ temp,
                         const void* __restrict__ theta,
                         float* __restrict__ consts) {
  const int l = threadIdx.x;  // 64 threads
  const ushort_t* u = (const ushort_t*)feat;
  float v0 = fabsf(bf2f(u[2 * l]));
  float v1 = fabsf(bf2f(u[2 * l + 1]));
  int ok = ((v0 > 1e-4f && v0 < 16.0f) ? 1 : 0) +
           ((v1 > 1e-4f && v1 < 16.0f) ? 1 : 0);
#pragma unroll
  for (int off = 1; off < 64; off <<= 1) ok += __shfl_xor(ok, off, 64);
  if (l == 0) {
    int isbf = (ok >= 100) ? 1 : 0;
    float tv, th;
    if (isbf) {
      tv = bf2f(((const ushort_t*)temp)[0]);
      th = bf2f(((const ushort_t*)theta)[0]);
    } else {
      tv = ((const float*)temp)[0];
      th = ((const float*)theta)[0];
    }
    consts[0] = (float)isbf;
    consts[1] = 1.0f + tv;
    consts[2] = 5.0f + th;
    consts[3] = 2.0f * (1.0f + tv) * 1.44269504088896341f;
  }
}

// ---------------------------------------------------------------------------
// prep: g = relu(x@glw+glb) (fp16), hT = (x@gnw+gnb)^T (fp16 [128][N]),
//       crow = (0.5*th - t*sq)*log2e.  One wave per row.
// ---------------------------------------------------------------------------
template <int L0>
__global__ __launch_bounds__(256) void prep_k(
    const void* __restrict__ xb, const float* __restrict__ msgp,
    const float* __restrict__ denp, const void* __restrict__ glw,
    const void* __restrict__ glb, const void* __restrict__ gnw,
    const void* __restrict__ gnb, const float* __restrict__ cst,
    _Float16* __restrict__ g, _Float16* __restrict__ hT,
    float* __restrict__ crow) {
  __shared__ float xr[4][128];
  const int w = threadIdx.x >> 6, l = threadIdx.x & 63;
  const int row = blockIdx.x * 4 + w;
  const int isbf = (cst[0] != 0.0f);
  float x0, x1;
  if (L0) {
    if (isbf) {
      const ushort_t* p = (const ushort_t*)xb;
      x0 = bf2f(p[row * 128 + 2 * l]);
      x1 = bf2f(p[row * 128 + 2 * l + 1]);
    } else {
      const float* p = (const float*)xb;
      x0 = p[row * 128 + 2 * l];
      x1 = p[row * 128 + 2 * l + 1];
    }
  } else {
    float m0 = 0.0f, m1 = 0.0f, d = 0.0f;
#pragma unroll
    for (int js = 0; js < JS; ++js) {
      const float* mp = msgp + (size_t)js * NN * HD + (size_t)row * HD;
      m0 += mp[2 * l];
      m1 += mp[2 * l + 1];
      d += denp[js * NN + row];
    }
    float rd = __builtin_amdgcn_rcpf(fmaxf(d, 1e-10f));
    x0 = fmaxf(m0 * rd, 0.0f);
    x1 = fmaxf(m1 * rd, 0.0f);
  }
  xr[w][2 * l] = x0;
  xr[w][2 * l + 1] = x1;
  __syncthreads();
  float ag = 0.0f, a0 = 0.0f, a1 = 0.0f;
  float bg, b0, b1;
  if (isbf) {
    const ushort_t* Wg = (const ushort_t*)glw;
    const ushort_t* Wn = (const ushort_t*)gnw;
#pragma unroll 8
    for (int k = 0; k < 128; ++k) {
      float xk = xr[w][k];
      ag = fmaf(xk, bf2f(Wg[k * 64 + l]), ag);
      a0 = fmaf(xk, bf2f(Wn[k * 128 + l]), a0);
      a1 = fmaf(xk, bf2f(Wn[k * 128 + 64 + l]), a1);
    }
    bg = bf2f(((const ushort_t*)glb)[l]);
    b0 = bf2f(((const ushort_t*)gnb)[l]);
    b1 = bf2f(((const ushort_t*)gnb)[64 + l]);
  } else {
    const float* Wg = (const float*)glw;
    const float* Wn = (const float*)gnw;
#pragma unroll 8
    for (int k = 0; k < 128; ++k) {
      float xk = xr[w][k];
      ag = fmaf(xk, Wg[k * 64 + l], ag);
      a0 = fmaf(xk, Wn[k * 128 + l], a0);
      a1 = fmaf(xk, Wn[k * 128 + 64 + l], a1);
    }
    bg = ((const float*)glb)[l];
    b0 = ((const float*)gnb)[l];
    b1 = ((const float*)gnb)[64 + l];
  }
  const float t = cst[1];
  const float th = cst[2];
  float gv = fmaxf(ag + bg, 0.0f);
  _Float16 gq = (_Float16)gv;
  g[(size_t)row * DL + l] = gq;
  float gf = (float)gq;
  float sq = gf * gf;
#pragma unroll
  for (int off = 1; off < 64; off <<= 1) sq += __shfl_xor(sq, off, 64);
  if (l == 0) crow[row] = (0.5f * th - t * sq) * 1.44269504088896341f;
  hT[(size_t)l * NN + row] = (_Float16)(a0 + b0);
  hT[(size_t)(l + 64) * NN + row] = (_Float16)(a1 + b1);
}

// ---------------------------------------------------------------------------
// fused sigmoid-attention: msgp[js] = P*H, denp[js] = P*1, P = 256*sigmoid.
// Double-buffered LDS staging; one barrier per K-iter.
// ---------------------------------------------------------------------------
__global__ __launch_bounds__(256, 2) void attn_main(
    const _Float16* __restrict__ g, const _Float16* __restrict__ hT,
    const float* __restrict__ crow, const float* __restrict__ cst,
    float* __restrict__ msgp, float* __restrict__ denp) {
  // per buffer: Gs 4096 halfs (8KB) + Hs 8192 halfs (16KB); x2 buffers
  __shared__ __align__(16) short SM[2 * 12288];

  const int tid = threadIdx.x;
  const int w = tid >> 6;
  const int l = tid & 63;
  const int ln = l & 31;
  const int hb = l >> 5;
  const int iw = blockIdx.x * BM + w * BMW;
  const int jb = blockIdx.y * JCH;
  const float s2 = cst[3];

  // persistent B-operand frags of G_i: B[n=i=lane&31][k=kf*16+hb*8+e]
  v8h Bi[4];
#pragma unroll
  for (int kf = 0; kf < 4; ++kf)
    Bi[kf] = *(const v8h*)(g + (size_t)(iw + ln) * DL + kf * 16 + hb * 8);

  const float ci = crow[iw + ln];

  v16f o[4];
#pragma unroll
  for (int mp = 0; mp < 4; ++mp)
#pragma unroll
    for (int r = 0; r < 16; ++r) o[mp][r] = 0.0f;

  float dp = 0.0f;

  // stage tile into buffer p
  auto stage = [&](int p, int j0) {
    char* Gb = (char*)(SM + p * 12288);
    char* Hb = (char*)(SM + p * 12288 + 4096);
#pragma unroll
    for (int oo = 0; oo < 2; ++oo) {
      int c = oo * 256 + tid;
      int jj = c >> 3, pc = c & 7;
      int kc = pc ^ (jj & 7);
      gld16(Gb + (oo * 256 + w * 64) * 16, g + (size_t)(j0 + jj) * DL + kc * 8);
    }
#pragma unroll
    for (int oo = 0; oo < 4; ++oo) {
      int c = oo * 256 + tid;
      int hc = c >> 3, pc = c & 7;
      int jc = pc ^ (hc & 7);
      gld16(Hb + (oo * 256 + w * 64) * 16, hT + (size_t)hc * NN + j0 + jc * 8);
    }
  };

  stage(0, jb);

#pragma unroll 1
  for (int itr = 0; itr < NITER; ++itr) {
    const int j0 = jb + itr * BN;
    const int p = itr & 1;
    __syncthreads();  // drains loads issued a full compute-phase ago
    if (itr + 1 < NITER) stage(p ^ 1, j0 + BN);
    _Float16* Gs = (_Float16*)(SM + p * 12288);
    _Float16* Hs = (_Float16*)(SM + p * 12288 + 4096);

#pragma unroll
    for (int jt = 0; jt < 2; ++jt) {
      float cj[16];
#pragma unroll
      for (int q2 = 0; q2 < 4; ++q2) {
        float4 f4 = *(const float4*)(crow + j0 + jt * 32 + q2 * 8 + 4 * hb);
        cj[q2 * 4 + 0] = f4.x;
        cj[q2 * 4 + 1] = f4.y;
        cj[q2 * 4 + 2] = f4.z;
        cj[q2 * 4 + 3] = f4.w;
      }
      // S^T = G_j * G_i^T
      v16f sv;
#pragma unroll
      for (int r = 0; r < 16; ++r) sv[r] = 0.0f;
#pragma unroll
      for (int kf = 0; kf < 4; ++kf) {
        int row = jt * 32 + ln;
        int kc = kf * 2 + hb;
        v8h a = *(const v8h*)(Gs + row * 64 + ((kc ^ (row & 7)) * 8));
        sv = __builtin_amdgcn_mfma_f32_32x32x16_f16(a, Bi[kf], sv, 0, 0, 0);
      }
      // sigmoid (x256); exp2 saturates cleanly, no clamps needed
      float pv[16];
      float dps = 0.0f;
#pragma unroll
      for (int r = 0; r < 16; ++r) {
        float arg = fmaf(s2, sv[r], ci) + cj[r];
        float e = __builtin_amdgcn_exp2f(-arg);
        float adj = 256.0f * __builtin_amdgcn_rcpf(1.0f + e);
        dps += adj;
        pv[r] = adj;
      }
      dp += dps;
      // P^T -> B-frags (pack + half-wave exchange), then O^T += H^T * P^T
#pragma unroll
      for (int kq = 0; kq < 2; ++kq) {
        int q = kq * 8;
        uint32 lo0 = pack2h(pv[q + 0], pv[q + 1]);
        uint32 lo1 = pack2h(pv[q + 2], pv[q + 3]);
        uint32 hi0 = pack2h(pv[q + 4], pv[q + 5]);
        uint32 hi1 = pack2h(pv[q + 6], pv[q + 7]);
        uint32 sl0 = (uint32)__shfl_xor((int)lo0, 32, 64);
        uint32 sl1 = (uint32)__shfl_xor((int)lo1, 32, 64);
        uint32 sh0 = (uint32)__shfl_xor((int)hi0, 32, 64);
        uint32 sh1 = (uint32)__shfl_xor((int)hi1, 32, 64);
        union { uint32 u[4]; v8h v; } b;
        b.u[0] = hb ? sh0 : lo0;
        b.u[1] = hb ? sh1 : lo1;
        b.u[2] = hb ? hi0 : sl0;
        b.u[3] = hb ? hi1 : sl1;
        int kc = (jt * 2 + kq) * 2 + hb;
#pragma unroll
        for (int mp = 0; mp < 4; ++mp) {
          int hc = mp * 32 + ln;
          v8h Ah = *(const v8h*)(Hs + hc * 64 + ((kc ^ (hc & 7)) * 8));
          o[mp] = __builtin_amdgcn_mfma_f32_32x32x16_f16(Ah, b.v, o[mp], 0, 0, 0);
        }
      }
    }
  }

  // epilogue: den partial (i on lanes)
  dp += __shfl_xor(dp, 32, 64);
  if (hb == 0) denp[blockIdx.y * NN + iw + ln] = dp;
  // msg partial: transpose 32x32 O^T tiles through LDS, coalesced stores
  __syncthreads();
  float* Tw = ((float*)SM) + w * (32 * 33);
  float* mout = msgp + (size_t)blockIdx.y * NN * HD;
#pragma unroll
  for (int mp = 0; mp < 4; ++mp) {
#pragma unroll
    for (int r = 0; r < 16; ++r) {
      int hl = (r & 3) + 8 * (r >> 2) + 4 * hb;
      Tw[ln * 33 + hl] = o[mp][r];
    }
#pragma unroll
    for (int rr = 0; rr < 16; ++rr) {
      int il = rr * 2 + hb;
      mout[(size_t)(iw + il) * HD + mp * 32 + ln] = Tw[il * 33 + ln];
    }
  }
}

// ---------------------------------------------------------------------------
// final: out = softmax((sum msgp / sum denp) @ out_w + out_b). 16 lanes/row.
// ---------------------------------------------------------------------------
__global__ __launch_bounds__(256) void final_k(
    const float* __restrict__ msgp, const float* __restrict__ denp,
    const void* __restrict__ ow, const void* __restrict__ ob,
    const float* __restrict__ cst, void* __restrict__ out) {
  __shared__ float Ws[1280];
  const int isbf = (cst[0] != 0.0f);
  if (isbf) {
    for (int i = threadIdx.x; i < 1280; i += 256) Ws[i] = bf2f(((const ushort_t*)ow)[i]);
  } else {
    for (int i = threadIdx.x; i < 1280; i += 256) Ws[i] = ((const float*)ow)[i];
  }
  __syncthreads();
  const int l16 = threadIdx.x & 15, grp = threadIdx.x >> 4;
  const int row = blockIdx.x * 16 + grp;
  float d = 0.0f;
#pragma unroll
  for (int js = 0; js < JS; ++js) d += denp[js * NN + row];
  const float rd = __builtin_amdgcn_rcpf(fmaxf(d, 1e-10f));
  float acc[10];
#pragma unroll
  for (int c = 0; c < 10; ++c) acc[c] = 0.0f;
#pragma unroll
  for (int kk = 0; kk < 8; ++kk) {
    int k = kk * 16 + l16;
    float m = 0.0f;
#pragma unroll
    for (int js = 0; js < JS; ++js)
      m += msgp[(size_t)js * NN * HD + (size_t)row * HD + k];
    float xv = m * rd;
    xv = fminf(fmaxf(xv, -1e6f), 1e6f);
#pragma unroll
    for (int c = 0; c < 10; ++c) acc[c] = fmaf(xv, Ws[k * 10 + c], acc[c]);
  }
  float bias[10];
  if (isbf) {
#pragma unroll
    for (int c = 0; c < 10; ++c) bias[c] = bf2f(((const ushort_t*)ob)[c]);
  } else {
#pragma unroll
    for (int c = 0; c < 10; ++c) bias[c] = ((const float*)ob)[c];
  }
#pragma unroll
  for (int c = 0; c < 10; ++c) {
#pragma unroll
    for (int off = 1; off < 16; off <<= 1) acc[c] += __shfl_xor(acc[c], off, 64);
    acc[c] += bias[c];
  }
  float m = acc[0];
#pragma unroll
  for (int c = 1; c < 10; ++c) m = fmaxf(m, acc[c]);
  float s = 0.0f, e[10];
#pragma unroll
  for (int c = 0; c < 10; ++c) {
    e[c] = __builtin_amdgcn_exp2f((acc[c] - m) * 1.44269504088896341f);
    s += e[c];
  }
  float rs = __builtin_amdgcn_rcpf(s);
  float mine = e[0];
#pragma unroll
  for (int c = 1; c < 10; ++c) mine = (l16 == c) ? e[c] : mine;
  if (l16 < 10) {
    float v = mine * rs;
    if (isbf) ((ushort_t*)out)[(size_t)row * 10 + l16] = f2bf(v);
    else ((float*)out)[(size_t)row * 10 + l16] = v;
  }
}

// ---------------------------------------------------------------------------
extern "C" void kernel_launch(void* const* d_in, const int* in_sizes, int n_in,
                              void* d_out, int out_size, void* d_ws,
                              size_t ws_size, hipStream_t stream) {
  const void* feat = d_in[0];
  const void* glw0 = d_in[1];
  const void* glb0 = d_in[2];
  const void* glw1 = d_in[3];
  const void* glb1 = d_in[4];
  const void* gnw0 = d_in[5];
  const void* gnb0 = d_in[6];
  const void* gnw1 = d_in[7];
  const void* gnb1 = d_in[8];
  const void* ow = d_in[9];
  const void* obv = d_in[10];
  const void* temp = d_in[11];
  const void* thet = d_in[12];

  char* ws = (char*)d_ws;
  _Float16* g = (_Float16*)ws;                          // 2 MB
  _Float16* hT = (_Float16*)(ws + (size_t)(2u << 20));  // 4 MB
  float* crow = (float*)(ws + (size_t)(6u << 20));      // 64 KB
  float* cst = (float*)(ws + (size_t)(6u << 20) + (1u << 16));  // 256 B
  float* msgp = (float*)(ws + (size_t)(7u << 20));      // 8 x 8 MB = 64 MB
  float* denp = (float*)(ws + (size_t)(71u << 20));     // 8 x 64 KB

  dim3 b256(256);
  detect_k<<<dim3(1), dim3(64), 0, stream>>>(feat, temp, thet, cst);
  // layer 0
  prep_k<1><<<dim3(NN / 4), b256, 0, stream>>>(feat, nullptr, nullptr, glw0,
                                               glb0, gnw0, gnb0, cst, g, hT,
                                               crow);
  attn_main<<<dim3(NN / BM, JS), b256, 0, stream>>>(g, hT, crow, cst, msgp,
                                                    denp);
  // layer 1
  prep_k<0><<<dim3(NN / 4), b256, 0, stream>>>(nullptr, msgp, denp, glw1, glb1,
                                               gnw1, gnb1, cst, g, hT, crow);
  attn_main<<<dim3(NN / BM, JS), b256, 0, stream>>>(g, hT, crow, cst, msgp,
                                                    denp);
  // output layer + softmax
  final_k<<<dim3(NN / 16), b256, 0, stream>>>(msgp, denp, ow, obv, cst, d_out);
}